// Round 9
// baseline (4496.706 us; speedup 1.0000x reference)
//
#include <hip/hip_runtime.h>
#include <hip/hip_bf16.h>
#include <hip/hip_fp16.h>

// Problem constants (fixed by the reference)
#define N_ 100000
#define MPAD 100096          // 782 * 128
#define E_ 400000
#define B_ 2048
#define H_ 300
#define KP_ 320              // H padded to mult of 32
#define L_ 5
#define EF_ 16
#define T_ 128
#define NPBAGG 32            // nodes per k_agg block (N_ % 32 == 0 -> 3125 blocks)
#define BNS 0.9999950000374997f  // 1/sqrt(1+1e-5)

typedef unsigned short ushort_t;
typedef short bf16x8 __attribute__((ext_vector_type(8)));
typedef float f32x4 __attribute__((ext_vector_type(4)));

__device__ __forceinline__ ushort_t f2b(float v) {
    unsigned u = __float_as_uint(v);
    unsigned r = (u + 0x7FFFu + ((u >> 16) & 1u)) >> 16;
    return (ushort_t)r;
}

__device__ __forceinline__ float b2f(ushort_t u) {
    return __uint_as_float(((unsigned)u) << 16);
}

__device__ __forceinline__ void gl_lds16(const void* g, void* l) {
    __builtin_amdgcn_global_load_lds(
        (const __attribute__((address_space(1))) void*)g,
        (__attribute__((address_space(3))) void*)l, 16, 0, 0);
}

// swizzled column for logical (row r, col j) in a swizzled bf16 buffer
__device__ __forceinline__ int swzcol(int r, int j) {
    int u = ((j >> 3) & 3) ^ ((r >> 1) & 3);
    return (j & ~31) | (u << 3) | (j & 7);
}

// ---------------- CSR build ----------------
__global__ void k_hist(const int* __restrict__ dst, int* __restrict__ degi, int E) {
    int e = blockIdx.x * blockDim.x + threadIdx.x;
    if (e < E) atomicAdd(&degi[dst[e]], 1);
}

__global__ void k_norm(const int* __restrict__ degi, float* __restrict__ nrm,
                       float* __restrict__ invdeg, int N) {
    int n = blockIdx.x * blockDim.x + threadIdx.x;
    if (n < N) {
        float d = (float)degi[n] + 1.0f;
        nrm[n] = 1.0f / sqrtf(d);
        invdeg[n] = 1.0f / d;
    }
}

__global__ void k_scan1(const int* __restrict__ in, int* __restrict__ out,
                        int* __restrict__ partial, int N) {
    __shared__ int s[1024];
    int i = blockIdx.x * 1024 + threadIdx.x;
    int v = (i < N) ? in[i] : 0;
    s[threadIdx.x] = v;
    __syncthreads();
    for (int off = 1; off < 1024; off <<= 1) {
        int t = (threadIdx.x >= off) ? s[threadIdx.x - off] : 0;
        __syncthreads();
        s[threadIdx.x] += t;
        __syncthreads();
    }
    if (i < N) out[i] = s[threadIdx.x] - v;  // exclusive
    if (threadIdx.x == 1023) partial[blockIdx.x] = s[1023];
}

// parallel scan of <=128 partials (one block of 128 threads)
__global__ void k_scan2(int* __restrict__ partial, int nb, int* __restrict__ totalOut) {
    __shared__ int sh[128];
    int t = threadIdx.x;
    int v = (t < nb) ? partial[t] : 0;
    sh[t] = v;
    __syncthreads();
    for (int off = 1; off < 128; off <<= 1) {
        int u = (t >= off) ? sh[t - off] : 0;
        __syncthreads();
        sh[t] += u;
        __syncthreads();
    }
    if (t < nb) partial[t] = sh[t] - v;  // exclusive
    if (t == 127) *totalOut = sh[127];
}

__global__ void k_scan3(int* __restrict__ out, const int* __restrict__ partial, int N) {
    int i = blockIdx.x * 1024 + threadIdx.x;
    if (i < N) out[i] += partial[blockIdx.x];
}

// scatter edges into CSR order; csrc_s = src*KP_ (pre-scaled row offset), cdst = dst node;
// pre-gather edge feats (f16, 32 B/edge) + per-edge norm
__global__ void k_scatter(const int* __restrict__ dst, const int* __restrict__ src,
                          const float* __restrict__ ef, const float* __restrict__ nrm,
                          int* __restrict__ cursor, int* __restrict__ csrc_s,
                          int* __restrict__ cdst,
                          ushort_t* __restrict__ ef16, float* __restrict__ en_csr, int E) {
    int e = blockIdx.x * blockDim.x + threadIdx.x;
    if (e >= E) return;
    int d = dst[e], s = src[e];
    int pos = atomicAdd(&cursor[d], 1);
    csrc_s[pos] = s * KP_;
    cdst[pos] = d;
    en_csr[pos] = nrm[s] * nrm[d];
    const float4* ep = (const float4*)&ef[(size_t)e * EF_];
    float4 e0 = ep[0], e1 = ep[1], e2 = ep[2], e3 = ep[3];
    uint4 ua, ub;
    ua.x = __builtin_bit_cast(unsigned, __floats2half2_rn(e0.x, e0.y));
    ua.y = __builtin_bit_cast(unsigned, __floats2half2_rn(e0.z, e0.w));
    ua.z = __builtin_bit_cast(unsigned, __floats2half2_rn(e1.x, e1.y));
    ua.w = __builtin_bit_cast(unsigned, __floats2half2_rn(e1.z, e1.w));
    ub.x = __builtin_bit_cast(unsigned, __floats2half2_rn(e2.x, e2.y));
    ub.y = __builtin_bit_cast(unsigned, __floats2half2_rn(e2.z, e2.w));
    ub.z = __builtin_bit_cast(unsigned, __floats2half2_rn(e3.x, e3.y));
    ub.w = __builtin_bit_cast(unsigned, __floats2half2_rn(e3.z, e3.w));
    uint4* op = (uint4*)&ef16[(size_t)pos * 16];
    op[0] = ua; op[1] = ub;
}

__global__ void k_rowstart(const int* __restrict__ gid, int* __restrict__ rs, int N, int B) {
    int b = blockIdx.x * blockDim.x + threadIdx.x;
    if (b <= B) {
        int lo = 0, hi = N;
        while (lo < hi) { int mid = (lo + hi) >> 1; if (gid[mid] < b) lo = mid + 1; else hi = mid; }
        rs[b] = lo;
    }
}

// ---------------- init ----------------
__global__ void k_hinit(const int* __restrict__ nt, const float* __restrict__ emb,
                        const float* __restrict__ vn_emb,
                        ushort_t* __restrict__ h_bf) {
    int n = blockIdx.x; int j = threadIdx.x;
    if (j >= H_) return;
    float v = emb[(size_t)nt[n] * H_ + j] + vn_emb[j];
    h_bf[(size_t)n * KP_ + swzcol(n, j)] = f2b(v);
}

__global__ void k_vninit(const float* __restrict__ vn_emb, float* __restrict__ vn) {
    int b = blockIdx.x; int j = threadIdx.x;
    if (j >= H_) return;
    vn[(size_t)b * H_ + j] = vn_emb[j];
}

// weight conversion: WT[l][n][k] = W[l][k][n], bf16, zero-padded, row-swizzled
__global__ void k_convW(const float* __restrict__ W, ushort_t* __restrict__ WT,
                        int nl, int K, int Nout, int KPv, int NPBv) {
    int UPR = KPv / 8;
    int tot = nl * NPBv * UPR;
    int idx = blockIdx.x * 256 + threadIdx.x;
    if (idx >= tot) return;
    int l = idx / (NPBv * UPR); int r = idx % (NPBv * UPR);
    int n = r / UPR; int ku = r % UPR;
    int k0 = ku * 8;
    int swz = (ku & 3) ^ ((n >> 1) & 3);
    size_t d = ((size_t)l * NPBv + n) * KPv + (size_t)(k0 & ~31) + swz * 8;
    #pragma unroll
    for (int i = 0; i < 8; i++) {
        int k = k0 + i;
        float v = (k < K && n < Nout) ? W[((size_t)l * K + k) * Nout + n] : 0.f;
        WT[d + i] = f2b(v);
    }
}

// We -> packed half2 pairs: Weh[l][k2][j] = (We[l][2k2][j], We[l][2k2+1][j])
__global__ void k_convWeh(const float* __restrict__ We, unsigned* __restrict__ Weh) {
    int idx = blockIdx.x * 256 + threadIdx.x;
    if (idx >= L_ * 8 * H_) return;
    int l = idx / (8 * H_); int r = idx % (8 * H_);
    int k2 = r / H_; int j = r % H_;
    float a = We[((size_t)l * EF_ + 2 * k2) * H_ + j];
    float b = We[((size_t)l * EF_ + 2 * k2 + 1) * H_ + j];
    Weh[((size_t)l * 8 + k2) * H_ + j] = __builtin_bit_cast(unsigned, __floats2half2_rn(a, b));
}

// ---------------- unified bf16 MFMA GEMM ----------------
#define MB 128
#define NB 128
__launch_bounds__(256)
__global__ void k_bgemm(const ushort_t* __restrict__ A, const ushort_t* __restrict__ BT,
                        int M, int Nn, int KP,
                        const float* __restrict__ bias, const float* __restrict__ scale,
                        const float* __restrict__ shift, int relu,
                        float* __restrict__ Cf, int ldf,
                        ushort_t* __restrict__ Cb, int ldb, int swzout) {
    __shared__ ushort_t As[MB * 32];
    __shared__ ushort_t Bs[NB * 32];
    int tid = threadIdx.x;
    int lane = tid & 63, wid = tid >> 6;
    int wm = wid >> 1, wn = wid & 1;
    int m0 = blockIdx.x * MB, n0 = blockIdx.y * NB;
    f32x4 acc[4][4];
    #pragma unroll
    for (int mi = 0; mi < 4; mi++)
        #pragma unroll
        for (int ni = 0; ni < 4; ni++)
            acc[mi][ni] = (f32x4){0.f, 0.f, 0.f, 0.f};

    const ushort_t* Ab = A + (size_t)m0 * KP;
    const ushort_t* Bb = BT + (size_t)n0 * KP;
    int lr = lane & 15, lg = lane >> 4;

    for (int k0 = 0; k0 < KP; k0 += 32) {
        #pragma unroll
        for (int i = 0; i < 2; i++) {
            int li = tid + 256 * i;
            int r = li >> 2, u = li & 3;
            gl_lds16(Ab + (size_t)r * KP + k0 + u * 8, &As[(size_t)(li & ~63) * 8]);
        }
        #pragma unroll
        for (int i = 0; i < 2; i++) {
            int li = tid + 256 * i;
            int r = li >> 2, u = li & 3;
            gl_lds16(Bb + (size_t)r * KP + k0 + u * 8, &Bs[(size_t)(li & ~63) * 8]);
        }
        __syncthreads();
        bf16x8 af[4], bv[4];
        #pragma unroll
        for (int mi = 0; mi < 4; mi++) {
            int rr = wm * 64 + mi * 16 + lr;
            int uu = lg ^ ((rr >> 1) & 3);
            af[mi] = *(const bf16x8*)&As[rr * 32 + uu * 8];
        }
        #pragma unroll
        for (int ni = 0; ni < 4; ni++) {
            int rr = wn * 64 + ni * 16 + lr;
            int uu = lg ^ ((rr >> 1) & 3);
            bv[ni] = *(const bf16x8*)&Bs[rr * 32 + uu * 8];
        }
        #pragma unroll
        for (int mi = 0; mi < 4; mi++)
            #pragma unroll
            for (int ni = 0; ni < 4; ni++)
                acc[mi][ni] = __builtin_amdgcn_mfma_f32_16x16x32_bf16(
                    af[mi], bv[ni], acc[mi][ni], 0, 0, 0);
        __syncthreads();
    }

    #pragma unroll
    for (int ni = 0; ni < 4; ni++) {
        int gn = n0 + wn * 64 + ni * 16 + lr;
        if (gn >= Nn) continue;
        float bvv = bias[gn];
        float sc = scale ? scale[gn] * BNS : 0.f;
        float sh = shift ? shift[gn] : 0.f;
        #pragma unroll
        for (int mi = 0; mi < 4; mi++) {
            #pragma unroll
            for (int t = 0; t < 4; t++) {
                int gm = m0 + wm * 64 + mi * 16 + lg * 4 + t;
                if (gm >= M) continue;
                float v = acc[mi][ni][t] + bvv;
                if (scale) v = v * sc + sh;
                if (relu) v = fmaxf(v, 0.f);
                if (Cf) Cf[(size_t)gm * ldf + gn] = v;
                else    Cb[(size_t)gm * ldb + (swzout ? swzcol(gm, gn) : gn)] = f2b(v);
            }
        }
    }
}

// ---------------- per-graph segment sum -> vtmp (swizzled bf16) ----------------
__global__ void k_vtmp(const ushort_t* __restrict__ h_bf, const float* __restrict__ vn,
                       const int* __restrict__ rs, ushort_t* __restrict__ vtmp_bf) {
    int b = blockIdx.x; int j = threadIdx.x;
    if (j >= H_) return;
    int s = rs[b], e = rs[b + 1];
    int jbase = (j & ~31) | (j & 7);
    int ju = (j >> 3) & 3;
    float acc = 0.f;
    for (int n = s; n < e; n++) {
        int col = jbase | ((ju ^ ((n >> 1) & 3)) << 3);
        acc += b2f(h_bf[(size_t)n * KP_ + col]);
    }
    vtmp_bf[(size_t)b * KP_ + swzcol(b, j)] = f2b(acc + vn[(size_t)b * H_ + j]);
}

// ---------------- fused readout: gmean (seg-sum/cnt) -> LDS -> head dot ----------------
__global__ void k_readout(const ushort_t* __restrict__ h_bf, const int* __restrict__ rs,
                          const float* __restrict__ pW, const float* __restrict__ pb,
                          float* __restrict__ out) {
    __shared__ float g[H_ + 4];
    int b = blockIdx.x; int j = threadIdx.x;
    int s = rs[b], e = rs[b + 1];
    if (j < H_) {
        int jbase = (j & ~31) | (j & 7);
        int ju = (j >> 3) & 3;
        float acc = 0.f;
        for (int n = s; n < e; n++) {
            int col = jbase | ((ju ^ ((n >> 1) & 3)) << 3);
            acc += b2f(h_bf[(size_t)n * KP_ + col]);
        }
        int cnt = e - s; if (cnt < 1) cnt = 1;
        g[j] = acc / (float)cnt;
    }
    __syncthreads();
    if (j < T_) {
        float o = pb[j];
        #pragma unroll 4
        for (int k = 0; k < H_; k++) o = fmaf(g[k], pW[(size_t)k * T_ + j], o);
        out[(size_t)b * T_ + j] = o;
    }
}

// ---------------- edge-streaming aggregation: 32 nodes/block, LDS accumulators ------------
__device__ __forceinline__ float eproj8(const uint4& ea, const uint4& eb,
                                        const __half2* wh, float bej) {
    __half2 hs = __floats2half2_rn(0.f, 0.f);
    hs = __hfma2(__builtin_bit_cast(__half2, ea.x), wh[0], hs);
    hs = __hfma2(__builtin_bit_cast(__half2, ea.y), wh[1], hs);
    hs = __hfma2(__builtin_bit_cast(__half2, ea.z), wh[2], hs);
    hs = __hfma2(__builtin_bit_cast(__half2, ea.w), wh[3], hs);
    hs = __hfma2(__builtin_bit_cast(__half2, eb.x), wh[4], hs);
    hs = __hfma2(__builtin_bit_cast(__half2, eb.y), wh[5], hs);
    hs = __hfma2(__builtin_bit_cast(__half2, eb.z), wh[6], hs);
    hs = __hfma2(__builtin_bit_cast(__half2, eb.w), wh[7], hs);
    return bej + __low2float(hs) + __high2float(hs);
}

__launch_bounds__(640)
__global__ void k_agg(const ushort_t* __restrict__ x_bf,
                      ushort_t* __restrict__ h_bf,
                      const int* __restrict__ off, const int* __restrict__ csrc_s,
                      const int* __restrict__ cdst,
                      const ushort_t* __restrict__ ef16, const float* __restrict__ en_csr,
                      const unsigned* __restrict__ Weh_l, const float* __restrict__ be_l,
                      const float* __restrict__ invdeg,
                      const float* __restrict__ root_l, const float* __restrict__ gamma_l,
                      const float* __restrict__ beta_l,
                      const float* __restrict__ vn_next, const int* __restrict__ gid,
                      int relu) {
    __shared__ float acc[NPBAGG * 304];
    int n0 = blockIdx.x * NPBAGG;
    int tid = threadIdx.x;
    int slot = tid / 320;            // wave-uniform: 5 waves per slot
    int j = tid - slot * 320;
    bool active = j < H_;

    // zero LDS accumulators
    for (int t = tid; t < NPBAGG * 304; t += 640) acc[t] = 0.f;
    __syncthreads();

    __half2 wh[8];
    float bej = 0.f;
    if (active) {
        #pragma unroll
        for (int k2 = 0; k2 < 8; k2++)
            wh[k2] = __builtin_bit_cast(__half2, Weh_l[k2 * H_ + j]);
        bej = be_l[j];
    }
    int estart = off[n0], eend = off[n0 + NPBAGG];

    // edge stream: slots alternate 4-edge quads; no loop-carried register deps
    for (int base = estart + slot * 4; base < eend; base += 8) {
        int i0 = base;
        int i1 = (base + 1 < eend) ? base + 1 : eend - 1;
        int i2 = (base + 2 < eend) ? base + 2 : eend - 1;
        int i3 = (base + 3 < eend) ? base + 3 : eend - 1;
        if (active) {
            int s0 = csrc_s[i0], s1 = csrc_s[i1], s2 = csrc_s[i2], s3 = csrc_s[i3];
            int d0 = cdst[i0] - n0, d1 = cdst[i1] - n0;
            int d2 = cdst[i2] - n0, d3 = cdst[i3] - n0;
            float en0 = en_csr[i0];
            float en1 = (base + 1 < eend) ? en_csr[i1] : 0.f;
            float en2 = (base + 2 < eend) ? en_csr[i2] : 0.f;
            float en3 = (base + 3 < eend) ? en_csr[i3] : 0.f;
            float xv0 = b2f(x_bf[(size_t)s0 + j]);
            float xv1 = b2f(x_bf[(size_t)s1 + j]);
            float xv2 = b2f(x_bf[(size_t)s2 + j]);
            float xv3 = b2f(x_bf[(size_t)s3 + j]);
            const uint4* p0 = (const uint4*)&ef16[(size_t)i0 * 16];
            const uint4* p1 = (const uint4*)&ef16[(size_t)i1 * 16];
            const uint4* p2 = (const uint4*)&ef16[(size_t)i2 * 16];
            const uint4* p3 = (const uint4*)&ef16[(size_t)i3 * 16];
            uint4 a0 = p0[0], b0 = p0[1];
            uint4 a1 = p1[0], b1 = p1[1];
            uint4 a2 = p2[0], b2 = p2[1];
            uint4 a3 = p3[0], b3 = p3[1];
            float m0 = en0 * fmaxf(xv0 + eproj8(a0, b0, wh, bej), 0.f);
            float m1 = en1 * fmaxf(xv1 + eproj8(a1, b1, wh, bej), 0.f);
            float m2 = en2 * fmaxf(xv2 + eproj8(a2, b2, wh, bej), 0.f);
            float m3 = en3 * fmaxf(xv3 + eproj8(a3, b3, wh, bej), 0.f);
            __hip_atomic_fetch_add(&acc[d0 * 304 + j], m0,
                                   __ATOMIC_RELAXED, __HIP_MEMORY_SCOPE_WORKGROUP);
            __hip_atomic_fetch_add(&acc[d1 * 304 + j], m1,
                                   __ATOMIC_RELAXED, __HIP_MEMORY_SCOPE_WORKGROUP);
            __hip_atomic_fetch_add(&acc[d2 * 304 + j], m2,
                                   __ATOMIC_RELAXED, __HIP_MEMORY_SCOPE_WORKGROUP);
            __hip_atomic_fetch_add(&acc[d3 * 304 + j], m3,
                                   __ATOMIC_RELAXED, __HIP_MEMORY_SCOPE_WORKGROUP);
        }
    }
    __syncthreads();

    // epilogue: each slot finishes 16 nodes (self term + BN [+relu] [+vn broadcast])
    if (!active) return;
    float rootj = root_l[j], gmj = gamma_l[j] * BNS, btj = beta_l[j];
    for (int r = 0; r < 16; r++) {
        int ln = r * 2 + slot;
        int n = n0 + ln;
        float a = acc[ln * 304 + j];
        float xn = b2f(x_bf[(size_t)n * KP_ + j]);
        float v = a + fmaxf(xn + rootj, 0.f) * invdeg[n];
        v = v * gmj + btj;
        if (relu) v = fmaxf(v, 0.f);
        if (vn_next) v += vn_next[(size_t)gid[n] * H_ + j];
        h_bf[(size_t)n * KP_ + swzcol(n, j)] = f2b(v);
    }
}

// ---------------- launch ----------------
extern "C" void kernel_launch(void* const* d_in, const int* in_sizes, int n_in,
                              void* d_out, int out_size, void* d_ws, size_t ws_size,
                              hipStream_t stream) {
    const int* node_types = (const int*)d_in[0];
    const int* src        = (const int*)d_in[1];
    const int* dst        = (const int*)d_in[2];
    const int* graph_ids  = (const int*)d_in[3];
    const float* edge_feats = (const float*)d_in[4];
    const float* node_emb   = (const float*)d_in[5];
    const float* Wn   = (const float*)d_in[6];
    const float* bn   = (const float*)d_in[7];
    const float* We   = (const float*)d_in[8];
    const float* be   = (const float*)d_in[9];
    const float* root = (const float*)d_in[10];
    const float* gamma = (const float*)d_in[11];
    const float* beta  = (const float*)d_in[12];
    const float* vn_emb = (const float*)d_in[13];
    const float* W1  = (const float*)d_in[14];
    const float* b1  = (const float*)d_in[15];
    const float* g1  = (const float*)d_in[16];
    const float* be1 = (const float*)d_in[17];
    const float* W2  = (const float*)d_in[18];
    const float* b2  = (const float*)d_in[19];
    const float* g2  = (const float*)d_in[20];
    const float* be2 = (const float*)d_in[21];
    const float* pW  = (const float*)d_in[22];
    const float* pb  = (const float*)d_in[23];
    float* out = (float*)d_out;

    // workspace carve-up (~157 MB; R1 proved >=253 MB available)
    char* p = (char*)d_ws;
    auto alloc = [&](size_t bytes) { void* q = (void*)p; p += (bytes + 255) & ~(size_t)255; return q; };
    ushort_t* h_bf   = (ushort_t*)alloc((size_t)MPAD * KP_ * 2);        // 64 MB (swizzled)
    ushort_t* x_bf   = (ushort_t*)alloc((size_t)MPAD * KP_ * 2);        // 64 MB (linear)
    ushort_t* ef16   = (ushort_t*)alloc((size_t)E_ * 16 * 2);           // 12.8 MB (f16 CSR)
    ushort_t* WnT    = (ushort_t*)alloc((size_t)L_ * 384 * KP_ * 2);
    unsigned* Weh    = (unsigned*)alloc((size_t)L_ * 8 * H_ * 4);
    ushort_t* W1T    = (ushort_t*)alloc((size_t)4 * 640 * KP_ * 2);
    ushort_t* W2T    = (ushort_t*)alloc((size_t)4 * 384 * 640 * 2);
    ushort_t* vtmp_bf= (ushort_t*)alloc((size_t)B_ * KP_ * 2);
    ushort_t* z_bf   = (ushort_t*)alloc((size_t)B_ * 640 * 2);
    float* vn    = (float*)alloc((size_t)B_ * H_ * 4);
    float* nrm   = (float*)alloc((size_t)N_ * 4);
    float* invdeg= (float*)alloc((size_t)N_ * 4);
    int* degi    = (int*)alloc((size_t)N_ * 4);
    int* csr_off = (int*)alloc((size_t)(N_ + 1) * 4);
    int* cursor  = (int*)alloc((size_t)N_ * 4);
    int* csrc_s  = (int*)alloc((size_t)E_ * 4);
    int* cdst    = (int*)alloc((size_t)E_ * 4);
    float* en_csr= (float*)alloc((size_t)E_ * 4);
    int* rs      = (int*)alloc((size_t)(B_ + 1) * 4);
    int* partial = (int*)alloc((size_t)128 * 4);

    const int SCAN_NB = (N_ + 1023) / 1024;  // 98

    // degree histogram + norms
    hipMemsetAsync(degi, 0, (size_t)N_ * 4, stream);
    k_hist<<<(E_ + 255) / 256, 256, 0, stream>>>(dst, degi, E_);
    k_norm<<<(N_ + 255) / 256, 256, 0, stream>>>(degi, nrm, invdeg, N_);

    // CSR offsets = exclusive scan of degi
    k_scan1<<<SCAN_NB, 1024, 0, stream>>>(degi, csr_off, partial, N_);
    k_scan2<<<1, 128, 0, stream>>>(partial, SCAN_NB, csr_off + N_);
    k_scan3<<<SCAN_NB, 1024, 0, stream>>>(csr_off, partial, N_);
    hipMemcpyAsync(cursor, csr_off, (size_t)N_ * 4, hipMemcpyDeviceToDevice, stream);
    k_scatter<<<(E_ + 255) / 256, 256, 0, stream>>>(dst, src, edge_feats, nrm,
                                                    cursor, csrc_s, cdst, ef16, en_csr, E_);

    // graph segment boundaries (graph_ids sorted)
    k_rowstart<<<(B_ + 1 + 255) / 256, 256, 0, stream>>>(graph_ids, rs, N_, B_);

    // weights -> bf16 transposed swizzled; We -> packed half2
    k_convW<<<(L_ * 384 * (KP_ / 8) + 255) / 256, 256, 0, stream>>>(Wn, WnT, L_, H_, H_, KP_, 384);
    k_convWeh<<<(L_ * 8 * H_ + 255) / 256, 256, 0, stream>>>(We, Weh);
    k_convW<<<(4 * 640 * (KP_ / 8) + 255) / 256, 256, 0, stream>>>(W1, W1T, 4, H_, 2 * H_, KP_, 640);
    k_convW<<<(4 * 384 * (640 / 8) + 255) / 256, 256, 0, stream>>>(W2, W2T, 4, 2 * H_, H_, 640, 384);

    // h = node_emb[nt] + vn_emb; vn = vn_emb
    k_hinit<<<N_, 320, 0, stream>>>(node_types, node_emb, vn_emb, h_bf);
    k_vninit<<<B_, 320, 0, stream>>>(vn_emb, vn);

    dim3 gx(MPAD / MB, 3);    // x GEMM: 782 x 3
    dim3 gz(B_ / MB, 5);      // z GEMM: 16 x 5
    dim3 gv(B_ / MB, 3);      // vn GEMM: 16 x 3

    for (int l = 0; l < L_; l++) {
        // x = h @ Wn[l] + bn[l]  -> bf16 LINEAR
        k_bgemm<<<gx, 256, 0, stream>>>(h_bf, WnT + (size_t)l * 384 * KP_,
                                        N_, H_, KP_,
                                        bn + (size_t)l * H_, nullptr, nullptr, 0,
                                        nullptr, 0, x_bf, KP_, 0);
        if (l < L_ - 1) {
            k_vtmp<<<B_, 320, 0, stream>>>(h_bf, vn, rs, vtmp_bf);
            // z = relu(bn1(vtmp @ W1 + b1)) -> bf16 swizzled [B][640]
            k_bgemm<<<gz, 256, 0, stream>>>(vtmp_bf, W1T + (size_t)l * 640 * KP_,
                                            B_, 2 * H_, KP_,
                                            b1 + (size_t)l * 2 * H_,
                                            g1 + (size_t)l * 2 * H_, be1 + (size_t)l * 2 * H_, 1,
                                            nullptr, 0, z_bf, 640, 1);
            // vn = relu(bn2(z @ W2 + b2)) -> fp32 [B][300]
            k_bgemm<<<gv, 256, 0, stream>>>(z_bf, W2T + (size_t)l * 384 * 640,
                                            B_, H_, 640,
                                            b2 + (size_t)l * H_,
                                            g2 + (size_t)l * H_, be2 + (size_t)l * H_, 1,
                                            vn, H_, nullptr, 0, 0);
        }
        // h = bn(agg + relu(x+root)*invdeg) (+relu/+vn_next if l<L-1)
        k_agg<<<N_ / NPBAGG, 640, 0, stream>>>(x_bf, h_bf, csr_off, csrc_s, cdst,
                                               ef16, en_csr,
                                               Weh + (size_t)l * 8 * H_, be + (size_t)l * H_,
                                               invdeg,
                                               root + (size_t)l * H_,
                                               gamma + (size_t)l * H_, beta + (size_t)l * H_,
                                               (l < L_ - 1) ? vn : nullptr, graph_ids,
                                               (l < L_ - 1) ? 1 : 0);
    }

    // fused readout: gmean -> head
    k_readout<<<B_, 320, 0, stream>>>(h_bf, rs, pW, pb, out);
}

// Round 10
// 1794.100 us; speedup vs baseline: 2.5064x; 2.5064x over previous
//
#include <hip/hip_runtime.h>
#include <hip/hip_bf16.h>
#include <hip/hip_fp16.h>

// Problem constants (fixed by the reference)
#define N_ 100000
#define MPAD 100096          // 782 * 128
#define E_ 400000
#define B_ 2048
#define H_ 300
#define KP_ 320              // H padded to mult of 32
#define L_ 5
#define EF_ 16
#define T_ 128
#define ANODES 4             // nodes per k_agg block
#define EMAX 96              // LDS-staged edge capacity per block
#define BNS 0.9999950000374997f  // 1/sqrt(1+1e-5)

typedef unsigned short ushort_t;
typedef short bf16x8 __attribute__((ext_vector_type(8)));
typedef float f32x4 __attribute__((ext_vector_type(4)));

__device__ __forceinline__ ushort_t f2b(float v) {
    unsigned u = __float_as_uint(v);
    unsigned r = (u + 0x7FFFu + ((u >> 16) & 1u)) >> 16;
    return (ushort_t)r;
}

__device__ __forceinline__ float b2f(ushort_t u) {
    return __uint_as_float(((unsigned)u) << 16);
}

__device__ __forceinline__ void gl_lds16(const void* g, void* l) {
    __builtin_amdgcn_global_load_lds(
        (const __attribute__((address_space(1))) void*)g,
        (__attribute__((address_space(3))) void*)l, 16, 0, 0);
}

// swizzled column for logical (row r, col j) in a swizzled bf16 buffer
__device__ __forceinline__ int swzcol(int r, int j) {
    int u = ((j >> 3) & 3) ^ ((r >> 1) & 3);
    return (j & ~31) | (u << 3) | (j & 7);
}

// ---------------- CSR build ----------------
__global__ void k_hist(const int* __restrict__ dst, int* __restrict__ degi, int E) {
    int e = blockIdx.x * blockDim.x + threadIdx.x;
    if (e < E) atomicAdd(&degi[dst[e]], 1);
}

__global__ void k_norm(const int* __restrict__ degi, float* __restrict__ nrm,
                       float* __restrict__ invdeg, int N) {
    int n = blockIdx.x * blockDim.x + threadIdx.x;
    if (n < N) {
        float d = (float)degi[n] + 1.0f;
        nrm[n] = 1.0f / sqrtf(d);
        invdeg[n] = 1.0f / d;
    }
}

__global__ void k_scan1(const int* __restrict__ in, int* __restrict__ out,
                        int* __restrict__ partial, int N) {
    __shared__ int s[1024];
    int i = blockIdx.x * 1024 + threadIdx.x;
    int v = (i < N) ? in[i] : 0;
    s[threadIdx.x] = v;
    __syncthreads();
    for (int off = 1; off < 1024; off <<= 1) {
        int t = (threadIdx.x >= off) ? s[threadIdx.x - off] : 0;
        __syncthreads();
        s[threadIdx.x] += t;
        __syncthreads();
    }
    if (i < N) out[i] = s[threadIdx.x] - v;  // exclusive
    if (threadIdx.x == 1023) partial[blockIdx.x] = s[1023];
}

__global__ void k_scan2(int* __restrict__ partial, int nb, int* __restrict__ totalOut) {
    __shared__ int sh[128];
    int t = threadIdx.x;
    int v = (t < nb) ? partial[t] : 0;
    sh[t] = v;
    __syncthreads();
    for (int off = 1; off < 128; off <<= 1) {
        int u = (t >= off) ? sh[t - off] : 0;
        __syncthreads();
        sh[t] += u;
        __syncthreads();
    }
    if (t < nb) partial[t] = sh[t] - v;  // exclusive
    if (t == 127) *totalOut = sh[127];
}

__global__ void k_scan3(int* __restrict__ out, const int* __restrict__ partial, int N) {
    int i = blockIdx.x * 1024 + threadIdx.x;
    if (i < N) out[i] += partial[blockIdx.x];
}

// scatter edges into CSR order; csrc_s = src*KP_; f16 edge feats + per-edge norm
__global__ void k_scatter(const int* __restrict__ dst, const int* __restrict__ src,
                          const float* __restrict__ ef, const float* __restrict__ nrm,
                          int* __restrict__ cursor, int* __restrict__ csrc_s,
                          ushort_t* __restrict__ ef16, float* __restrict__ en_csr, int E) {
    int e = blockIdx.x * blockDim.x + threadIdx.x;
    if (e >= E) return;
    int d = dst[e], s = src[e];
    int pos = atomicAdd(&cursor[d], 1);
    csrc_s[pos] = s * KP_;
    en_csr[pos] = nrm[s] * nrm[d];
    const float4* ep = (const float4*)&ef[(size_t)e * EF_];
    float4 e0 = ep[0], e1 = ep[1], e2 = ep[2], e3 = ep[3];
    uint4 ua, ub;
    ua.x = __builtin_bit_cast(unsigned, __floats2half2_rn(e0.x, e0.y));
    ua.y = __builtin_bit_cast(unsigned, __floats2half2_rn(e0.z, e0.w));
    ua.z = __builtin_bit_cast(unsigned, __floats2half2_rn(e1.x, e1.y));
    ua.w = __builtin_bit_cast(unsigned, __floats2half2_rn(e1.z, e1.w));
    ub.x = __builtin_bit_cast(unsigned, __floats2half2_rn(e2.x, e2.y));
    ub.y = __builtin_bit_cast(unsigned, __floats2half2_rn(e2.z, e2.w));
    ub.z = __builtin_bit_cast(unsigned, __floats2half2_rn(e3.x, e3.y));
    ub.w = __builtin_bit_cast(unsigned, __floats2half2_rn(e3.z, e3.w));
    uint4* op = (uint4*)&ef16[(size_t)pos * 16];
    op[0] = ua; op[1] = ub;
}

__global__ void k_rowstart(const int* __restrict__ gid, int* __restrict__ rs, int N, int B) {
    int b = blockIdx.x * blockDim.x + threadIdx.x;
    if (b <= B) {
        int lo = 0, hi = N;
        while (lo < hi) { int mid = (lo + hi) >> 1; if (gid[mid] < b) lo = mid + 1; else hi = mid; }
        rs[b] = lo;
    }
}

// ---------------- init ----------------
// writes ALL 320 cols (pad cols = 0) so later vector reads of pads are safe
__global__ void k_hinit(const int* __restrict__ nt, const float* __restrict__ emb,
                        const float* __restrict__ vn_emb,
                        ushort_t* __restrict__ h_bf) {
    int n = blockIdx.x; int j = threadIdx.x;
    if (j >= KP_) return;
    float v = (j < H_) ? emb[(size_t)nt[n] * H_ + j] + vn_emb[j] : 0.f;
    h_bf[(size_t)n * KP_ + swzcol(n, j)] = f2b(v);
}

__global__ void k_vninit(const float* __restrict__ vn_emb, float* __restrict__ vn) {
    int b = blockIdx.x; int j = threadIdx.x;
    if (j >= H_) return;
    vn[(size_t)b * H_ + j] = vn_emb[j];
}

// weight conversion: WT[l][n][k] = W[l][k][n], bf16, zero-padded, row-swizzled
__global__ void k_convW(const float* __restrict__ W, ushort_t* __restrict__ WT,
                        int nl, int K, int Nout, int KPv, int NPBv) {
    int UPR = KPv / 8;
    int tot = nl * NPBv * UPR;
    int idx = blockIdx.x * 256 + threadIdx.x;
    if (idx >= tot) return;
    int l = idx / (NPBv * UPR); int r = idx % (NPBv * UPR);
    int n = r / UPR; int ku = r % UPR;
    int k0 = ku * 8;
    int swz = (ku & 3) ^ ((n >> 1) & 3);
    size_t d = ((size_t)l * NPBv + n) * KPv + (size_t)(k0 & ~31) + swz * 8;
    #pragma unroll
    for (int i = 0; i < 8; i++) {
        int k = k0 + i;
        float v = (k < K && n < Nout) ? W[((size_t)l * K + k) * Nout + n] : 0.f;
        WT[d + i] = f2b(v);
    }
}

// We -> packed half2 pairs: Weh[l][k2][j] = (We[l][2k2][j], We[l][2k2+1][j])
__global__ void k_convWeh(const float* __restrict__ We, unsigned* __restrict__ Weh) {
    int idx = blockIdx.x * 256 + threadIdx.x;
    if (idx >= L_ * 8 * H_) return;
    int l = idx / (8 * H_); int r = idx % (8 * H_);
    int k2 = r / H_; int j = r % H_;
    float a = We[((size_t)l * EF_ + 2 * k2) * H_ + j];
    float b = We[((size_t)l * EF_ + 2 * k2 + 1) * H_ + j];
    Weh[((size_t)l * 8 + k2) * H_ + j] = __builtin_bit_cast(unsigned, __floats2half2_rn(a, b));
}

// ---------------- unified bf16 MFMA GEMM ----------------
#define MB 128
#define NB 128
__launch_bounds__(256)
__global__ void k_bgemm(const ushort_t* __restrict__ A, const ushort_t* __restrict__ BT,
                        int M, int Nn, int KP,
                        const float* __restrict__ bias, const float* __restrict__ scale,
                        const float* __restrict__ shift, int relu,
                        float* __restrict__ Cf, int ldf,
                        ushort_t* __restrict__ Cb, int ldb, int swzout) {
    __shared__ ushort_t As[MB * 32];
    __shared__ ushort_t Bs[NB * 32];
    int tid = threadIdx.x;
    int lane = tid & 63, wid = tid >> 6;
    int wm = wid >> 1, wn = wid & 1;
    int m0 = blockIdx.x * MB, n0 = blockIdx.y * NB;
    f32x4 acc[4][4];
    #pragma unroll
    for (int mi = 0; mi < 4; mi++)
        #pragma unroll
        for (int ni = 0; ni < 4; ni++)
            acc[mi][ni] = (f32x4){0.f, 0.f, 0.f, 0.f};

    const ushort_t* Ab = A + (size_t)m0 * KP;
    const ushort_t* Bb = BT + (size_t)n0 * KP;
    int lr = lane & 15, lg = lane >> 4;

    for (int k0 = 0; k0 < KP; k0 += 32) {
        #pragma unroll
        for (int i = 0; i < 2; i++) {
            int li = tid + 256 * i;
            int r = li >> 2, u = li & 3;
            gl_lds16(Ab + (size_t)r * KP + k0 + u * 8, &As[(size_t)(li & ~63) * 8]);
        }
        #pragma unroll
        for (int i = 0; i < 2; i++) {
            int li = tid + 256 * i;
            int r = li >> 2, u = li & 3;
            gl_lds16(Bb + (size_t)r * KP + k0 + u * 8, &Bs[(size_t)(li & ~63) * 8]);
        }
        __syncthreads();
        bf16x8 af[4], bv[4];
        #pragma unroll
        for (int mi = 0; mi < 4; mi++) {
            int rr = wm * 64 + mi * 16 + lr;
            int uu = lg ^ ((rr >> 1) & 3);
            af[mi] = *(const bf16x8*)&As[rr * 32 + uu * 8];
        }
        #pragma unroll
        for (int ni = 0; ni < 4; ni++) {
            int rr = wn * 64 + ni * 16 + lr;
            int uu = lg ^ ((rr >> 1) & 3);
            bv[ni] = *(const bf16x8*)&Bs[rr * 32 + uu * 8];
        }
        #pragma unroll
        for (int mi = 0; mi < 4; mi++)
            #pragma unroll
            for (int ni = 0; ni < 4; ni++)
                acc[mi][ni] = __builtin_amdgcn_mfma_f32_16x16x32_bf16(
                    af[mi], bv[ni], acc[mi][ni], 0, 0, 0);
        __syncthreads();
    }

    #pragma unroll
    for (int ni = 0; ni < 4; ni++) {
        int gn = n0 + wn * 64 + ni * 16 + lr;
        if (gn >= Nn) continue;
        float bvv = bias[gn];
        float sc = scale ? scale[gn] * BNS : 0.f;
        float sh = shift ? shift[gn] : 0.f;
        #pragma unroll
        for (int mi = 0; mi < 4; mi++) {
            #pragma unroll
            for (int t = 0; t < 4; t++) {
                int gm = m0 + wm * 64 + mi * 16 + lg * 4 + t;
                if (gm >= M) continue;
                float v = acc[mi][ni][t] + bvv;
                if (scale) v = v * sc + sh;
                if (relu) v = fmaxf(v, 0.f);
                if (Cf) Cf[(size_t)gm * ldf + gn] = v;
                else    Cb[(size_t)gm * ldb + (swzout ? swzcol(gm, gn) : gn)] = f2b(v);
            }
        }
    }
}

// ---------------- vectorized per-graph segment sum -> vtmp (swizzled bf16) ----------------
// 256 threads: 240 accumulate (unit u = t%40, row-stripe rr = t/40 of 6), LDS reduce.
__launch_bounds__(256)
__global__ void k_vtmp(const ushort_t* __restrict__ h_bf, const float* __restrict__ vn,
                       const int* __restrict__ rs, ushort_t* __restrict__ vtmp_bf) {
    __shared__ float red[40 * 8 * 6];
    int b = blockIdx.x;
    int t = threadIdx.x;
    int u = t % 40, rr = t / 40;
    int s = rs[b], e = rs[b + 1];
    if (rr < 6) {
        float a8[8] = {0.f, 0.f, 0.f, 0.f, 0.f, 0.f, 0.f, 0.f};
        int g = u >> 2, w = u & 3;
        for (int n = s + rr; n < e; n += 6) {
            int phys = (g << 2) | (w ^ ((n >> 1) & 3));
            bf16x8 hv = *(const bf16x8*)&h_bf[(size_t)n * KP_ + phys * 8];
            #pragma unroll
            for (int k = 0; k < 8; k++) a8[k] += b2f((ushort_t)hv[k]);
        }
        #pragma unroll
        for (int k = 0; k < 8; k++) red[(u * 8 + k) * 6 + rr] = a8[k];
    }
    __syncthreads();
    if (t < 40) {
        int g = t >> 2, w = t & 3;
        int phys = (g << 2) | (w ^ ((b >> 1) & 3));
        ushort_t ov[8];
        #pragma unroll
        for (int k = 0; k < 8; k++) {
            int j = t * 8 + k;
            float sum = 0.f;
            #pragma unroll
            for (int r = 0; r < 6; r++) sum += red[(t * 8 + k) * 6 + r];
            float val = (j < H_) ? sum + vn[(size_t)b * H_ + j] : 0.f;
            ov[k] = f2b(val);
        }
        *(bf16x8*)&vtmp_bf[(size_t)b * KP_ + phys * 8] = *(bf16x8*)ov;
    }
}

// ---------------- vectorized fused readout: gmean -> head ----------------
__launch_bounds__(256)
__global__ void k_readout(const ushort_t* __restrict__ h_bf, const int* __restrict__ rs,
                          const float* __restrict__ pW, const float* __restrict__ pb,
                          float* __restrict__ out) {
    __shared__ float red[40 * 8 * 6];
    __shared__ float gg[320];
    int b = blockIdx.x;
    int t = threadIdx.x;
    int u = t % 40, rr = t / 40;
    int s = rs[b], e = rs[b + 1];
    if (rr < 6) {
        float a8[8] = {0.f, 0.f, 0.f, 0.f, 0.f, 0.f, 0.f, 0.f};
        int g = u >> 2, w = u & 3;
        for (int n = s + rr; n < e; n += 6) {
            int phys = (g << 2) | (w ^ ((n >> 1) & 3));
            bf16x8 hv = *(const bf16x8*)&h_bf[(size_t)n * KP_ + phys * 8];
            #pragma unroll
            for (int k = 0; k < 8; k++) a8[k] += b2f((ushort_t)hv[k]);
        }
        #pragma unroll
        for (int k = 0; k < 8; k++) red[(u * 8 + k) * 6 + rr] = a8[k];
    }
    __syncthreads();
    if (t < 40) {
        int cnt = e - s; if (cnt < 1) cnt = 1;
        float ic = 1.f / (float)cnt;
        #pragma unroll
        for (int k = 0; k < 8; k++) {
            float sum = 0.f;
            #pragma unroll
            for (int r = 0; r < 6; r++) sum += red[(t * 8 + k) * 6 + r];
            gg[t * 8 + k] = sum * ic;
        }
    }
    __syncthreads();
    if (t < T_) {
        float o = pb[t];
        #pragma unroll 4
        for (int k = 0; k < H_; k++) o = fmaf(gg[k], pW[(size_t)k * T_ + t], o);
        out[(size_t)b * T_ + t] = o;
    }
}

// ---------------- edge aggregation: 4 nodes/block, LDS-staged edge metadata ------------
__device__ __forceinline__ float eproj8(const uint4& ea, const uint4& eb,
                                        const __half2* wh, float bej) {
    __half2 hs = __floats2half2_rn(0.f, 0.f);
    hs = __hfma2(__builtin_bit_cast(__half2, ea.x), wh[0], hs);
    hs = __hfma2(__builtin_bit_cast(__half2, ea.y), wh[1], hs);
    hs = __hfma2(__builtin_bit_cast(__half2, ea.z), wh[2], hs);
    hs = __hfma2(__builtin_bit_cast(__half2, ea.w), wh[3], hs);
    hs = __hfma2(__builtin_bit_cast(__half2, eb.x), wh[4], hs);
    hs = __hfma2(__builtin_bit_cast(__half2, eb.y), wh[5], hs);
    hs = __hfma2(__builtin_bit_cast(__half2, eb.z), wh[6], hs);
    hs = __hfma2(__builtin_bit_cast(__half2, eb.w), wh[7], hs);
    return bej + __low2float(hs) + __high2float(hs);
}

__launch_bounds__(320)
__global__ void k_agg(const ushort_t* __restrict__ x_bf,
                      ushort_t* __restrict__ h_bf,
                      const int* __restrict__ off, const int* __restrict__ csrc_s,
                      const ushort_t* __restrict__ ef16, const float* __restrict__ en_csr,
                      const unsigned* __restrict__ Weh_l, const float* __restrict__ be_l,
                      const float* __restrict__ invdeg,
                      const float* __restrict__ root_l, const float* __restrict__ gamma_l,
                      const float* __restrict__ beta_l,
                      const float* __restrict__ vn_next, const int* __restrict__ gid,
                      int relu) {
    __shared__ int s_src[EMAX];
    __shared__ float s_en[EMAX];
    __shared__ unsigned s_ef[EMAX * 8];
    int n0 = blockIdx.x * ANODES;
    int tid = threadIdx.x;
    int j = tid;

    int o0 = off[n0], o1 = off[n0 + 1], o2 = off[n0 + 2],
        o3 = off[n0 + 3], o4 = off[n0 + 4];
    int estart = o0, cnt = o4 - o0;
    bool lds_ok = cnt <= EMAX;

    // stage edge metadata (coalesced; all threads)
    if (lds_ok) {
        const unsigned* efu = (const unsigned*)ef16;
        for (int t = tid; t < cnt; t += 320) {
            s_src[t] = csrc_s[estart + t];
            s_en[t] = en_csr[estart + t];
        }
        for (int uu = tid; uu < 8 * cnt; uu += 320)
            s_ef[uu] = efu[(size_t)estart * 8 + uu];
    }
    __syncthreads();

    if (j >= H_) return;
    __half2 wh[8];
    #pragma unroll
    for (int k2 = 0; k2 < 8; k2++)
        wh[k2] = __builtin_bit_cast(__half2, Weh_l[k2 * H_ + j]);
    float bej = be_l[j];

    // self x loads for all 4 nodes (independent, issued early)
    float xn[ANODES];
    #pragma unroll
    for (int ln = 0; ln < ANODES; ln++)
        xn[ln] = b2f(x_bf[(size_t)(n0 + ln) * KP_ + j]);

    int re[ANODES] = {o1 - o0, o2 - o0, o3 - o0, o4 - o0};
    float accv[ANODES];
    int rel = 0;
    #pragma unroll
    for (int ln = 0; ln < ANODES; ln++) {
        int rend = re[ln];
        float a = 0.f;
        for (int q = rel; q < rend; q += 4) {
            int i0 = q;
            int i1 = (q + 1 < rend) ? q + 1 : rend - 1;
            int i2 = (q + 2 < rend) ? q + 2 : rend - 1;
            int i3 = (q + 3 < rend) ? q + 3 : rend - 1;
            int s0 = lds_ok ? s_src[i0] : csrc_s[estart + i0];
            int s1 = lds_ok ? s_src[i1] : csrc_s[estart + i1];
            int s2 = lds_ok ? s_src[i2] : csrc_s[estart + i2];
            int s3 = lds_ok ? s_src[i3] : csrc_s[estart + i3];
            float en0 = lds_ok ? s_en[i0] : en_csr[estart + i0];
            float en1 = (q + 1 < rend) ? (lds_ok ? s_en[i1] : en_csr[estart + i1]) : 0.f;
            float en2 = (q + 2 < rend) ? (lds_ok ? s_en[i2] : en_csr[estart + i2]) : 0.f;
            float en3 = (q + 3 < rend) ? (lds_ok ? s_en[i3] : en_csr[estart + i3]) : 0.f;
            float xv0 = b2f(x_bf[(size_t)s0 + j]);
            float xv1 = b2f(x_bf[(size_t)s1 + j]);
            float xv2 = b2f(x_bf[(size_t)s2 + j]);
            float xv3 = b2f(x_bf[(size_t)s3 + j]);
            uint4 a0, b0, a1, b1, a2, b2, a3, b3;
            if (lds_ok) {
                a0 = *(const uint4*)&s_ef[i0 * 8]; b0 = *(const uint4*)&s_ef[i0 * 8 + 4];
                a1 = *(const uint4*)&s_ef[i1 * 8]; b1 = *(const uint4*)&s_ef[i1 * 8 + 4];
                a2 = *(const uint4*)&s_ef[i2 * 8]; b2 = *(const uint4*)&s_ef[i2 * 8 + 4];
                a3 = *(const uint4*)&s_ef[i3 * 8]; b3 = *(const uint4*)&s_ef[i3 * 8 + 4];
            } else {
                const uint4* p0 = (const uint4*)&ef16[(size_t)(estart + i0) * 16];
                const uint4* p1 = (const uint4*)&ef16[(size_t)(estart + i1) * 16];
                const uint4* p2 = (const uint4*)&ef16[(size_t)(estart + i2) * 16];
                const uint4* p3 = (const uint4*)&ef16[(size_t)(estart + i3) * 16];
                a0 = p0[0]; b0 = p0[1]; a1 = p1[0]; b1 = p1[1];
                a2 = p2[0]; b2 = p2[1]; a3 = p3[0]; b3 = p3[1];
            }
            a = fmaf(en0, fmaxf(xv0 + eproj8(a0, b0, wh, bej), 0.f), a);
            a = fmaf(en1, fmaxf(xv1 + eproj8(a1, b1, wh, bej), 0.f), a);
            a = fmaf(en2, fmaxf(xv2 + eproj8(a2, b2, wh, bej), 0.f), a);
            a = fmaf(en3, fmaxf(xv3 + eproj8(a3, b3, wh, bej), 0.f), a);
        }
        accv[ln] = a;
        rel = rend;
    }

    float rootj = root_l[j], gmj = gamma_l[j] * BNS, btj = beta_l[j];
    #pragma unroll
    for (int ln = 0; ln < ANODES; ln++) {
        int n = n0 + ln;
        float v = accv[ln] + fmaxf(xn[ln] + rootj, 0.f) * invdeg[n];
        v = v * gmj + btj;
        if (relu) v = fmaxf(v, 0.f);
        if (vn_next) v += vn_next[(size_t)gid[n] * H_ + j];
        h_bf[(size_t)n * KP_ + swzcol(n, j)] = f2b(v);
    }
}

// ---------------- launch ----------------
extern "C" void kernel_launch(void* const* d_in, const int* in_sizes, int n_in,
                              void* d_out, int out_size, void* d_ws, size_t ws_size,
                              hipStream_t stream) {
    const int* node_types = (const int*)d_in[0];
    const int* src        = (const int*)d_in[1];
    const int* dst        = (const int*)d_in[2];
    const int* graph_ids  = (const int*)d_in[3];
    const float* edge_feats = (const float*)d_in[4];
    const float* node_emb   = (const float*)d_in[5];
    const float* Wn   = (const float*)d_in[6];
    const float* bn   = (const float*)d_in[7];
    const float* We   = (const float*)d_in[8];
    const float* be   = (const float*)d_in[9];
    const float* root = (const float*)d_in[10];
    const float* gamma = (const float*)d_in[11];
    const float* beta  = (const float*)d_in[12];
    const float* vn_emb = (const float*)d_in[13];
    const float* W1  = (const float*)d_in[14];
    const float* b1  = (const float*)d_in[15];
    const float* g1  = (const float*)d_in[16];
    const float* be1 = (const float*)d_in[17];
    const float* W2  = (const float*)d_in[18];
    const float* b2  = (const float*)d_in[19];
    const float* g2  = (const float*)d_in[20];
    const float* be2 = (const float*)d_in[21];
    const float* pW  = (const float*)d_in[22];
    const float* pb  = (const float*)d_in[23];
    float* out = (float*)d_out;

    // workspace carve-up (~155 MB; R1 proved >=253 MB available)
    char* p = (char*)d_ws;
    auto alloc = [&](size_t bytes) { void* q = (void*)p; p += (bytes + 255) & ~(size_t)255; return q; };
    ushort_t* h_bf   = (ushort_t*)alloc((size_t)MPAD * KP_ * 2);        // 64 MB (swizzled)
    ushort_t* x_bf   = (ushort_t*)alloc((size_t)MPAD * KP_ * 2);        // 64 MB (linear)
    ushort_t* ef16   = (ushort_t*)alloc((size_t)E_ * 16 * 2);           // 12.8 MB (f16 CSR)
    ushort_t* WnT    = (ushort_t*)alloc((size_t)L_ * 384 * KP_ * 2);
    unsigned* Weh    = (unsigned*)alloc((size_t)L_ * 8 * H_ * 4);
    ushort_t* W1T    = (ushort_t*)alloc((size_t)4 * 640 * KP_ * 2);
    ushort_t* W2T    = (ushort_t*)alloc((size_t)4 * 384 * 640 * 2);
    ushort_t* vtmp_bf= (ushort_t*)alloc((size_t)B_ * KP_ * 2);
    ushort_t* z_bf   = (ushort_t*)alloc((size_t)B_ * 640 * 2);
    float* vn    = (float*)alloc((size_t)B_ * H_ * 4);
    float* nrm   = (float*)alloc((size_t)N_ * 4);
    float* invdeg= (float*)alloc((size_t)N_ * 4);
    int* degi    = (int*)alloc((size_t)N_ * 4);
    int* csr_off = (int*)alloc((size_t)(N_ + 1) * 4);
    int* cursor  = (int*)alloc((size_t)N_ * 4);
    int* csrc_s  = (int*)alloc((size_t)E_ * 4);
    float* en_csr= (float*)alloc((size_t)E_ * 4);
    int* rs      = (int*)alloc((size_t)(B_ + 1) * 4);
    int* partial = (int*)alloc((size_t)128 * 4);

    const int SCAN_NB = (N_ + 1023) / 1024;  // 98

    // degree histogram + norms
    hipMemsetAsync(degi, 0, (size_t)N_ * 4, stream);
    k_hist<<<(E_ + 255) / 256, 256, 0, stream>>>(dst, degi, E_);
    k_norm<<<(N_ + 255) / 256, 256, 0, stream>>>(degi, nrm, invdeg, N_);

    // CSR offsets = exclusive scan of degi
    k_scan1<<<SCAN_NB, 1024, 0, stream>>>(degi, csr_off, partial, N_);
    k_scan2<<<1, 128, 0, stream>>>(partial, SCAN_NB, csr_off + N_);
    k_scan3<<<SCAN_NB, 1024, 0, stream>>>(csr_off, partial, N_);
    hipMemcpyAsync(cursor, csr_off, (size_t)N_ * 4, hipMemcpyDeviceToDevice, stream);
    k_scatter<<<(E_ + 255) / 256, 256, 0, stream>>>(dst, src, edge_feats, nrm,
                                                    cursor, csrc_s, ef16, en_csr, E_);

    // graph segment boundaries (graph_ids sorted)
    k_rowstart<<<(B_ + 1 + 255) / 256, 256, 0, stream>>>(graph_ids, rs, N_, B_);

    // weights -> bf16 transposed swizzled; We -> packed half2
    k_convW<<<(L_ * 384 * (KP_ / 8) + 255) / 256, 256, 0, stream>>>(Wn, WnT, L_, H_, H_, KP_, 384);
    k_convWeh<<<(L_ * 8 * H_ + 255) / 256, 256, 0, stream>>>(We, Weh);
    k_convW<<<(4 * 640 * (KP_ / 8) + 255) / 256, 256, 0, stream>>>(W1, W1T, 4, H_, 2 * H_, KP_, 640);
    k_convW<<<(4 * 384 * (640 / 8) + 255) / 256, 256, 0, stream>>>(W2, W2T, 4, 2 * H_, H_, 640, 384);

    // h = node_emb[nt] + vn_emb (pads zeroed); vn = vn_emb
    k_hinit<<<N_, 320, 0, stream>>>(node_types, node_emb, vn_emb, h_bf);
    k_vninit<<<B_, 320, 0, stream>>>(vn_emb, vn);

    dim3 gx(MPAD / MB, 3);    // x GEMM: 782 x 3
    dim3 gz(B_ / MB, 5);      // z GEMM: 16 x 5
    dim3 gv(B_ / MB, 3);      // vn GEMM: 16 x 3

    for (int l = 0; l < L_; l++) {
        // x = h @ Wn[l] + bn[l]  -> bf16 LINEAR
        k_bgemm<<<gx, 256, 0, stream>>>(h_bf, WnT + (size_t)l * 384 * KP_,
                                        N_, H_, KP_,
                                        bn + (size_t)l * H_, nullptr, nullptr, 0,
                                        nullptr, 0, x_bf, KP_, 0);
        if (l < L_ - 1) {
            k_vtmp<<<B_, 256, 0, stream>>>(h_bf, vn, rs, vtmp_bf);
            // z = relu(bn1(vtmp @ W1 + b1)) -> bf16 swizzled [B][640]
            k_bgemm<<<gz, 256, 0, stream>>>(vtmp_bf, W1T + (size_t)l * 640 * KP_,
                                            B_, 2 * H_, KP_,
                                            b1 + (size_t)l * 2 * H_,
                                            g1 + (size_t)l * 2 * H_, be1 + (size_t)l * 2 * H_, 1,
                                            nullptr, 0, z_bf, 640, 1);
            // vn = relu(bn2(z @ W2 + b2)) -> fp32 [B][300]
            k_bgemm<<<gv, 256, 0, stream>>>(z_bf, W2T + (size_t)l * 384 * 640,
                                            B_, H_, 640,
                                            b2 + (size_t)l * H_,
                                            g2 + (size_t)l * H_, be2 + (size_t)l * H_, 1,
                                            vn, H_, nullptr, 0, 0);
        }
        // h = bn(agg + relu(x+root)*invdeg) (+relu/+vn_next if l<L-1)
        k_agg<<<N_ / ANODES, 320, 0, stream>>>(x_bf, h_bf, csr_off, csrc_s,
                                               ef16, en_csr,
                                               Weh + (size_t)l * 8 * H_, be + (size_t)l * H_,
                                               invdeg,
                                               root + (size_t)l * H_,
                                               gamma + (size_t)l * H_, beta + (size_t)l * H_,
                                               (l < L_ - 1) ? vn : nullptr, graph_ids,
                                               (l < L_ - 1) ? 1 : 0);
    }

    // fused readout: gmean -> head
    k_readout<<<B_, 256, 0, stream>>>(h_bf, rs, pW, pb, out);
}

// Round 11
// 1771.535 us; speedup vs baseline: 2.5383x; 1.0127x over previous
//
#include <hip/hip_runtime.h>
#include <hip/hip_bf16.h>
#include <hip/hip_fp16.h>

// Problem constants (fixed by the reference)
#define N_ 100000
#define MPAD 100096          // 782 * 128
#define E_ 400000
#define B_ 2048
#define H_ 300
#define KP_ 320              // H padded to mult of 32
#define L_ 5
#define EF_ 16
#define T_ 128
#define ANODES 8             // nodes per k_agg block (N_ % 8 == 0 -> 12500 blocks)
#define EMAX 128             // LDS-staged edge capacity per block (Poisson(32): P(>128)~0)
#define BNS 0.9999950000374997f  // 1/sqrt(1+1e-5)

typedef unsigned short ushort_t;
typedef short bf16x8 __attribute__((ext_vector_type(8)));
typedef float f32x4 __attribute__((ext_vector_type(4)));
typedef _Float16 h2f __attribute__((ext_vector_type(2)));

__device__ __forceinline__ ushort_t f2b(float v) {
    unsigned u = __float_as_uint(v);
    unsigned r = (u + 0x7FFFu + ((u >> 16) & 1u)) >> 16;
    return (ushort_t)r;
}

__device__ __forceinline__ float b2f(ushort_t u) {
    return __uint_as_float(((unsigned)u) << 16);
}

__device__ __forceinline__ void gl_lds16(const void* g, void* l) {
    __builtin_amdgcn_global_load_lds(
        (const __attribute__((address_space(1))) void*)g,
        (__attribute__((address_space(3))) void*)l, 16, 0, 0);
}

// swizzled column for logical (row r, col j) in a swizzled bf16 buffer
__device__ __forceinline__ int swzcol(int r, int j) {
    int u = ((j >> 3) & 3) ^ ((r >> 1) & 3);
    return (j & ~31) | (u << 3) | (j & 7);
}

// ---------------- CSR build ----------------
__global__ void k_hist(const int* __restrict__ dst, int* __restrict__ degi, int E) {
    int e = blockIdx.x * blockDim.x + threadIdx.x;
    if (e < E) atomicAdd(&degi[dst[e]], 1);
}

__global__ void k_norm(const int* __restrict__ degi, float* __restrict__ nrm,
                       float* __restrict__ invdeg, int N) {
    int n = blockIdx.x * blockDim.x + threadIdx.x;
    if (n < N) {
        float d = (float)degi[n] + 1.0f;
        nrm[n] = 1.0f / sqrtf(d);
        invdeg[n] = 1.0f / d;
    }
}

__global__ void k_scan1(const int* __restrict__ in, int* __restrict__ out,
                        int* __restrict__ partial, int N) {
    __shared__ int s[1024];
    int i = blockIdx.x * 1024 + threadIdx.x;
    int v = (i < N) ? in[i] : 0;
    s[threadIdx.x] = v;
    __syncthreads();
    for (int off = 1; off < 1024; off <<= 1) {
        int t = (threadIdx.x >= off) ? s[threadIdx.x - off] : 0;
        __syncthreads();
        s[threadIdx.x] += t;
        __syncthreads();
    }
    if (i < N) out[i] = s[threadIdx.x] - v;  // exclusive
    if (threadIdx.x == 1023) partial[blockIdx.x] = s[1023];
}

__global__ void k_scan2(int* __restrict__ partial, int nb, int* __restrict__ totalOut) {
    __shared__ int sh[128];
    int t = threadIdx.x;
    int v = (t < nb) ? partial[t] : 0;
    sh[t] = v;
    __syncthreads();
    for (int off = 1; off < 128; off <<= 1) {
        int u = (t >= off) ? sh[t - off] : 0;
        __syncthreads();
        sh[t] += u;
        __syncthreads();
    }
    if (t < nb) partial[t] = sh[t] - v;  // exclusive
    if (t == 127) *totalOut = sh[127];
}

__global__ void k_scan3(int* __restrict__ out, const int* __restrict__ partial, int N) {
    int i = blockIdx.x * 1024 + threadIdx.x;
    if (i < N) out[i] += partial[blockIdx.x];
}

// scatter edges into CSR order; meta = (src*KP_, en bits); f16 edge feats
__global__ void k_scatter(const int* __restrict__ dst, const int* __restrict__ src,
                          const float* __restrict__ ef, const float* __restrict__ nrm,
                          int* __restrict__ cursor, int2* __restrict__ meta,
                          ushort_t* __restrict__ ef16, int E) {
    int e = blockIdx.x * blockDim.x + threadIdx.x;
    if (e >= E) return;
    int d = dst[e], s = src[e];
    int pos = atomicAdd(&cursor[d], 1);
    int2 md;
    md.x = s * KP_;
    md.y = __float_as_int(nrm[s] * nrm[d]);
    meta[pos] = md;
    const float4* ep = (const float4*)&ef[(size_t)e * EF_];
    float4 e0 = ep[0], e1 = ep[1], e2 = ep[2], e3 = ep[3];
    uint4 ua, ub;
    ua.x = __builtin_bit_cast(unsigned, __floats2half2_rn(e0.x, e0.y));
    ua.y = __builtin_bit_cast(unsigned, __floats2half2_rn(e0.z, e0.w));
    ua.z = __builtin_bit_cast(unsigned, __floats2half2_rn(e1.x, e1.y));
    ua.w = __builtin_bit_cast(unsigned, __floats2half2_rn(e1.z, e1.w));
    ub.x = __builtin_bit_cast(unsigned, __floats2half2_rn(e2.x, e2.y));
    ub.y = __builtin_bit_cast(unsigned, __floats2half2_rn(e2.z, e2.w));
    ub.z = __builtin_bit_cast(unsigned, __floats2half2_rn(e3.x, e3.y));
    ub.w = __builtin_bit_cast(unsigned, __floats2half2_rn(e3.z, e3.w));
    uint4* op = (uint4*)&ef16[(size_t)pos * 16];
    op[0] = ua; op[1] = ub;
}

__global__ void k_rowstart(const int* __restrict__ gid, int* __restrict__ rs, int N, int B) {
    int b = blockIdx.x * blockDim.x + threadIdx.x;
    if (b <= B) {
        int lo = 0, hi = N;
        while (lo < hi) { int mid = (lo + hi) >> 1; if (gid[mid] < b) lo = mid + 1; else hi = mid; }
        rs[b] = lo;
    }
}

// ---------------- init ----------------
// writes ALL 320 cols (pad cols = 0) so later vector reads of pads are safe
__global__ void k_hinit(const int* __restrict__ nt, const float* __restrict__ emb,
                        const float* __restrict__ vn_emb,
                        ushort_t* __restrict__ h_bf) {
    int n = blockIdx.x; int j = threadIdx.x;
    if (j >= KP_) return;
    float v = (j < H_) ? emb[(size_t)nt[n] * H_ + j] + vn_emb[j] : 0.f;
    h_bf[(size_t)n * KP_ + swzcol(n, j)] = f2b(v);
}

__global__ void k_vninit(const float* __restrict__ vn_emb, float* __restrict__ vn) {
    int b = blockIdx.x; int j = threadIdx.x;
    if (j >= H_) return;
    vn[(size_t)b * H_ + j] = vn_emb[j];
}

// weight conversion: WT[l][n][k] = W[l][k][n], bf16, zero-padded, row-swizzled
__global__ void k_convW(const float* __restrict__ W, ushort_t* __restrict__ WT,
                        int nl, int K, int Nout, int KPv, int NPBv) {
    int UPR = KPv / 8;
    int tot = nl * NPBv * UPR;
    int idx = blockIdx.x * 256 + threadIdx.x;
    if (idx >= tot) return;
    int l = idx / (NPBv * UPR); int r = idx % (NPBv * UPR);
    int n = r / UPR; int ku = r % UPR;
    int k0 = ku * 8;
    int swz = (ku & 3) ^ ((n >> 1) & 3);
    size_t d = ((size_t)l * NPBv + n) * KPv + (size_t)(k0 & ~31) + swz * 8;
    #pragma unroll
    for (int i = 0; i < 8; i++) {
        int k = k0 + i;
        float v = (k < K && n < Nout) ? W[((size_t)l * K + k) * Nout + n] : 0.f;
        WT[d + i] = f2b(v);
    }
}

// We -> packed half2 pairs: Weh[l][k2][j] = (We[l][2k2][j], We[l][2k2+1][j])
__global__ void k_convWeh(const float* __restrict__ We, unsigned* __restrict__ Weh) {
    int idx = blockIdx.x * 256 + threadIdx.x;
    if (idx >= L_ * 8 * H_) return;
    int l = idx / (8 * H_); int r = idx % (8 * H_);
    int k2 = r / H_; int j = r % H_;
    float a = We[((size_t)l * EF_ + 2 * k2) * H_ + j];
    float b = We[((size_t)l * EF_ + 2 * k2 + 1) * H_ + j];
    Weh[((size_t)l * 8 + k2) * H_ + j] = __builtin_bit_cast(unsigned, __floats2half2_rn(a, b));
}

// ---------------- unified bf16 MFMA GEMM ----------------
#define MB 128
#define NB 128
__launch_bounds__(256)
__global__ void k_bgemm(const ushort_t* __restrict__ A, const ushort_t* __restrict__ BT,
                        int M, int Nn, int KP,
                        const float* __restrict__ bias, const float* __restrict__ scale,
                        const float* __restrict__ shift, int relu,
                        float* __restrict__ Cf, int ldf,
                        ushort_t* __restrict__ Cb, int ldb, int swzout) {
    __shared__ ushort_t As[MB * 32];
    __shared__ ushort_t Bs[NB * 32];
    int tid = threadIdx.x;
    int lane = tid & 63, wid = tid >> 6;
    int wm = wid >> 1, wn = wid & 1;
    int m0 = blockIdx.x * MB, n0 = blockIdx.y * NB;
    f32x4 acc[4][4];
    #pragma unroll
    for (int mi = 0; mi < 4; mi++)
        #pragma unroll
        for (int ni = 0; ni < 4; ni++)
            acc[mi][ni] = (f32x4){0.f, 0.f, 0.f, 0.f};

    const ushort_t* Ab = A + (size_t)m0 * KP;
    const ushort_t* Bb = BT + (size_t)n0 * KP;
    int lr = lane & 15, lg = lane >> 4;

    for (int k0 = 0; k0 < KP; k0 += 32) {
        #pragma unroll
        for (int i = 0; i < 2; i++) {
            int li = tid + 256 * i;
            int r = li >> 2, u = li & 3;
            gl_lds16(Ab + (size_t)r * KP + k0 + u * 8, &As[(size_t)(li & ~63) * 8]);
        }
        #pragma unroll
        for (int i = 0; i < 2; i++) {
            int li = tid + 256 * i;
            int r = li >> 2, u = li & 3;
            gl_lds16(Bb + (size_t)r * KP + k0 + u * 8, &Bs[(size_t)(li & ~63) * 8]);
        }
        __syncthreads();
        bf16x8 af[4], bv[4];
        #pragma unroll
        for (int mi = 0; mi < 4; mi++) {
            int rr = wm * 64 + mi * 16 + lr;
            int uu = lg ^ ((rr >> 1) & 3);
            af[mi] = *(const bf16x8*)&As[rr * 32 + uu * 8];
        }
        #pragma unroll
        for (int ni = 0; ni < 4; ni++) {
            int rr = wn * 64 + ni * 16 + lr;
            int uu = lg ^ ((rr >> 1) & 3);
            bv[ni] = *(const bf16x8*)&Bs[rr * 32 + uu * 8];
        }
        #pragma unroll
        for (int mi = 0; mi < 4; mi++)
            #pragma unroll
            for (int ni = 0; ni < 4; ni++)
                acc[mi][ni] = __builtin_amdgcn_mfma_f32_16x16x32_bf16(
                    af[mi], bv[ni], acc[mi][ni], 0, 0, 0);
        __syncthreads();
    }

    #pragma unroll
    for (int ni = 0; ni < 4; ni++) {
        int gn = n0 + wn * 64 + ni * 16 + lr;
        if (gn >= Nn) continue;
        float bvv = bias[gn];
        float sc = scale ? scale[gn] * BNS : 0.f;
        float sh = shift ? shift[gn] : 0.f;
        #pragma unroll
        for (int mi = 0; mi < 4; mi++) {
            #pragma unroll
            for (int t = 0; t < 4; t++) {
                int gm = m0 + wm * 64 + mi * 16 + lg * 4 + t;
                if (gm >= M) continue;
                float v = acc[mi][ni][t] + bvv;
                if (scale) v = v * sc + sh;
                if (relu) v = fmaxf(v, 0.f);
                if (Cf) Cf[(size_t)gm * ldf + gn] = v;
                else    Cb[(size_t)gm * ldb + (swzout ? swzcol(gm, gn) : gn)] = f2b(v);
            }
        }
    }
}

// ---------------- vectorized per-graph segment sum -> vtmp (swizzled bf16) ----------------
__launch_bounds__(256)
__global__ void k_vtmp(const ushort_t* __restrict__ h_bf, const float* __restrict__ vn,
                       const int* __restrict__ rs, ushort_t* __restrict__ vtmp_bf) {
    __shared__ float red[40 * 8 * 6];
    int b = blockIdx.x;
    int t = threadIdx.x;
    int u = t % 40, rr = t / 40;
    int s = rs[b], e = rs[b + 1];
    if (rr < 6) {
        float a8[8] = {0.f, 0.f, 0.f, 0.f, 0.f, 0.f, 0.f, 0.f};
        int g = u >> 2, w = u & 3;
        for (int n = s + rr; n < e; n += 6) {
            int phys = (g << 2) | (w ^ ((n >> 1) & 3));
            bf16x8 hv = *(const bf16x8*)&h_bf[(size_t)n * KP_ + phys * 8];
            #pragma unroll
            for (int k = 0; k < 8; k++) a8[k] += b2f((ushort_t)hv[k]);
        }
        #pragma unroll
        for (int k = 0; k < 8; k++) red[(u * 8 + k) * 6 + rr] = a8[k];
    }
    __syncthreads();
    if (t < 40) {
        int g = t >> 2, w = t & 3;
        int phys = (g << 2) | (w ^ ((b >> 1) & 3));
        ushort_t ov[8];
        #pragma unroll
        for (int k = 0; k < 8; k++) {
            int j = t * 8 + k;
            float sum = 0.f;
            #pragma unroll
            for (int r = 0; r < 6; r++) sum += red[(t * 8 + k) * 6 + r];
            float val = (j < H_) ? sum + vn[(size_t)b * H_ + j] : 0.f;
            ov[k] = f2b(val);
        }
        *(bf16x8*)&vtmp_bf[(size_t)b * KP_ + phys * 8] = *(bf16x8*)ov;
    }
}

// ---------------- vectorized fused readout: gmean -> head ----------------
__launch_bounds__(256)
__global__ void k_readout(const ushort_t* __restrict__ h_bf, const int* __restrict__ rs,
                          const float* __restrict__ pW, const float* __restrict__ pb,
                          float* __restrict__ out) {
    __shared__ float red[40 * 8 * 6];
    __shared__ float gg[320];
    int b = blockIdx.x;
    int t = threadIdx.x;
    int u = t % 40, rr = t / 40;
    int s = rs[b], e = rs[b + 1];
    if (rr < 6) {
        float a8[8] = {0.f, 0.f, 0.f, 0.f, 0.f, 0.f, 0.f, 0.f};
        int g = u >> 2, w = u & 3;
        for (int n = s + rr; n < e; n += 6) {
            int phys = (g << 2) | (w ^ ((n >> 1) & 3));
            bf16x8 hv = *(const bf16x8*)&h_bf[(size_t)n * KP_ + phys * 8];
            #pragma unroll
            for (int k = 0; k < 8; k++) a8[k] += b2f((ushort_t)hv[k]);
        }
        #pragma unroll
        for (int k = 0; k < 8; k++) red[(u * 8 + k) * 6 + rr] = a8[k];
    }
    __syncthreads();
    if (t < 40) {
        int cnt = e - s; if (cnt < 1) cnt = 1;
        float ic = 1.f / (float)cnt;
        #pragma unroll
        for (int k = 0; k < 8; k++) {
            float sum = 0.f;
            #pragma unroll
            for (int r = 0; r < 6; r++) sum += red[(t * 8 + k) * 6 + r];
            gg[t * 8 + k] = sum * ic;
        }
    }
    __syncthreads();
    if (t < T_) {
        float o = pb[t];
        #pragma unroll 4
        for (int k = 0; k < H_; k++) o = fmaf(gg[k], pW[(size_t)k * T_ + t], o);
        out[(size_t)b * T_ + t] = o;
    }
}

// ---------------- edge aggregation: 8 nodes/block, LDS metadata, fdot2 ------------
__device__ __forceinline__ float eproj8d(const uint4& ea, const uint4& eb,
                                         const h2f* wh, float bej) {
    float ev = bej;
    ev = __builtin_amdgcn_fdot2(__builtin_bit_cast(h2f, ea.x), wh[0], ev, false);
    ev = __builtin_amdgcn_fdot2(__builtin_bit_cast(h2f, ea.y), wh[1], ev, false);
    ev = __builtin_amdgcn_fdot2(__builtin_bit_cast(h2f, ea.z), wh[2], ev, false);
    ev = __builtin_amdgcn_fdot2(__builtin_bit_cast(h2f, ea.w), wh[3], ev, false);
    ev = __builtin_amdgcn_fdot2(__builtin_bit_cast(h2f, eb.x), wh[4], ev, false);
    ev = __builtin_amdgcn_fdot2(__builtin_bit_cast(h2f, eb.y), wh[5], ev, false);
    ev = __builtin_amdgcn_fdot2(__builtin_bit_cast(h2f, eb.z), wh[6], ev, false);
    ev = __builtin_amdgcn_fdot2(__builtin_bit_cast(h2f, eb.w), wh[7], ev, false);
    return ev;
}

__launch_bounds__(320)
__global__ void k_agg(const ushort_t* __restrict__ x_bf,
                      ushort_t* __restrict__ h_bf,
                      const int* __restrict__ off, const int2* __restrict__ meta,
                      const ushort_t* __restrict__ ef16,
                      const unsigned* __restrict__ Weh_l, const float* __restrict__ be_l,
                      const float* __restrict__ invdeg,
                      const float* __restrict__ root_l, const float* __restrict__ gamma_l,
                      const float* __restrict__ beta_l,
                      const float* __restrict__ vn_next, const int* __restrict__ gid,
                      int relu) {
    __shared__ int2 s_md[EMAX];
    __shared__ unsigned s_ef[EMAX * 8];
    int n0 = blockIdx.x * ANODES;
    int tid = threadIdx.x;
    int j = tid;

    int offv[ANODES + 1];
    #pragma unroll
    for (int k = 0; k <= ANODES; k++) offv[k] = off[n0 + k];
    int estart = offv[0], cnt = offv[ANODES] - estart;
    bool lds_ok = cnt <= EMAX;

    // stage edge metadata (coalesced; all threads)
    if (lds_ok) {
        const unsigned* efu = (const unsigned*)ef16;
        for (int t = tid; t < cnt; t += 320) s_md[t] = meta[estart + t];
        for (int uu = tid; uu < 8 * cnt; uu += 320)
            s_ef[uu] = efu[(size_t)estart * 8 + uu];
    }
    __syncthreads();

    if (j >= H_) return;
    h2f wh[8];
    #pragma unroll
    for (int k2 = 0; k2 < 8; k2++)
        wh[k2] = __builtin_bit_cast(h2f, Weh_l[k2 * H_ + j]);
    float bej = be_l[j];

    // self x loads for all nodes (independent, issued early)
    float xn[ANODES];
    #pragma unroll
    for (int ln = 0; ln < ANODES; ln++)
        xn[ln] = b2f(x_bf[(size_t)(n0 + ln) * KP_ + j]);

    float accv[ANODES];
    #pragma unroll
    for (int ln = 0; ln < ANODES; ln++) {
        int rel = offv[ln] - estart, rend = offv[ln + 1] - estart;
        float a = 0.f;
        for (int q = rel; q < rend; q += 4) {
            int i0 = q;
            int i1 = (q + 1 < rend) ? q + 1 : rend - 1;
            int i2 = (q + 2 < rend) ? q + 2 : rend - 1;
            int i3 = (q + 3 < rend) ? q + 3 : rend - 1;
            int2 m0 = lds_ok ? s_md[i0] : meta[estart + i0];
            int2 m1 = lds_ok ? s_md[i1] : meta[estart + i1];
            int2 m2 = lds_ok ? s_md[i2] : meta[estart + i2];
            int2 m3 = lds_ok ? s_md[i3] : meta[estart + i3];
            float en0 = __int_as_float(m0.y);
            float en1 = (q + 1 < rend) ? __int_as_float(m1.y) : 0.f;
            float en2 = (q + 2 < rend) ? __int_as_float(m2.y) : 0.f;
            float en3 = (q + 3 < rend) ? __int_as_float(m3.y) : 0.f;
            float xv0 = b2f(x_bf[(size_t)m0.x + j]);
            float xv1 = b2f(x_bf[(size_t)m1.x + j]);
            float xv2 = b2f(x_bf[(size_t)m2.x + j]);
            float xv3 = b2f(x_bf[(size_t)m3.x + j]);
            uint4 a0, b0, a1, b1, a2, b2, a3, b3;
            if (lds_ok) {
                a0 = *(const uint4*)&s_ef[i0 * 8]; b0 = *(const uint4*)&s_ef[i0 * 8 + 4];
                a1 = *(const uint4*)&s_ef[i1 * 8]; b1 = *(const uint4*)&s_ef[i1 * 8 + 4];
                a2 = *(const uint4*)&s_ef[i2 * 8]; b2 = *(const uint4*)&s_ef[i2 * 8 + 4];
                a3 = *(const uint4*)&s_ef[i3 * 8]; b3 = *(const uint4*)&s_ef[i3 * 8 + 4];
            } else {
                const uint4* p0 = (const uint4*)&ef16[(size_t)(estart + i0) * 16];
                const uint4* p1 = (const uint4*)&ef16[(size_t)(estart + i1) * 16];
                const uint4* p2 = (const uint4*)&ef16[(size_t)(estart + i2) * 16];
                const uint4* p3 = (const uint4*)&ef16[(size_t)(estart + i3) * 16];
                a0 = p0[0]; b0 = p0[1]; a1 = p1[0]; b1 = p1[1];
                a2 = p2[0]; b2 = p2[1]; a3 = p3[0]; b3 = p3[1];
            }
            a = fmaf(en0, fmaxf(xv0 + eproj8d(a0, b0, wh, bej), 0.f), a);
            a = fmaf(en1, fmaxf(xv1 + eproj8d(a1, b1, wh, bej), 0.f), a);
            a = fmaf(en2, fmaxf(xv2 + eproj8d(a2, b2, wh, bej), 0.f), a);
            a = fmaf(en3, fmaxf(xv3 + eproj8d(a3, b3, wh, bej), 0.f), a);
        }
        accv[ln] = a;
    }

    float rootj = root_l[j], gmj = gamma_l[j] * BNS, btj = beta_l[j];
    #pragma unroll
    for (int ln = 0; ln < ANODES; ln++) {
        int n = n0 + ln;
        float v = accv[ln] + fmaxf(xn[ln] + rootj, 0.f) * invdeg[n];
        v = v * gmj + btj;
        if (relu) v = fmaxf(v, 0.f);
        if (vn_next) v += vn_next[(size_t)gid[n] * H_ + j];
        h_bf[(size_t)n * KP_ + swzcol(n, j)] = f2b(v);
    }
}

// ---------------- launch ----------------
extern "C" void kernel_launch(void* const* d_in, const int* in_sizes, int n_in,
                              void* d_out, int out_size, void* d_ws, size_t ws_size,
                              hipStream_t stream) {
    const int* node_types = (const int*)d_in[0];
    const int* src        = (const int*)d_in[1];
    const int* dst        = (const int*)d_in[2];
    const int* graph_ids  = (const int*)d_in[3];
    const float* edge_feats = (const float*)d_in[4];
    const float* node_emb   = (const float*)d_in[5];
    const float* Wn   = (const float*)d_in[6];
    const float* bn   = (const float*)d_in[7];
    const float* We   = (const float*)d_in[8];
    const float* be   = (const float*)d_in[9];
    const float* root = (const float*)d_in[10];
    const float* gamma = (const float*)d_in[11];
    const float* beta  = (const float*)d_in[12];
    const float* vn_emb = (const float*)d_in[13];
    const float* W1  = (const float*)d_in[14];
    const float* b1  = (const float*)d_in[15];
    const float* g1  = (const float*)d_in[16];
    const float* be1 = (const float*)d_in[17];
    const float* W2  = (const float*)d_in[18];
    const float* b2  = (const float*)d_in[19];
    const float* g2  = (const float*)d_in[20];
    const float* be2 = (const float*)d_in[21];
    const float* pW  = (const float*)d_in[22];
    const float* pb  = (const float*)d_in[23];
    float* out = (float*)d_out;

    // workspace carve-up (~155 MB; R1 proved >=253 MB available)
    char* p = (char*)d_ws;
    auto alloc = [&](size_t bytes) { void* q = (void*)p; p += (bytes + 255) & ~(size_t)255; return q; };
    ushort_t* h_bf   = (ushort_t*)alloc((size_t)MPAD * KP_ * 2);        // 64 MB (swizzled)
    ushort_t* x_bf   = (ushort_t*)alloc((size_t)MPAD * KP_ * 2);        // 64 MB (linear)
    ushort_t* ef16   = (ushort_t*)alloc((size_t)E_ * 16 * 2);           // 12.8 MB (f16 CSR)
    ushort_t* WnT    = (ushort_t*)alloc((size_t)L_ * 384 * KP_ * 2);
    unsigned* Weh    = (unsigned*)alloc((size_t)L_ * 8 * H_ * 4);
    ushort_t* W1T    = (ushort_t*)alloc((size_t)4 * 640 * KP_ * 2);
    ushort_t* W2T    = (ushort_t*)alloc((size_t)4 * 384 * 640 * 2);
    ushort_t* vtmp_bf= (ushort_t*)alloc((size_t)B_ * KP_ * 2);
    ushort_t* z_bf   = (ushort_t*)alloc((size_t)B_ * 640 * 2);
    float* vn    = (float*)alloc((size_t)B_ * H_ * 4);
    float* nrm   = (float*)alloc((size_t)N_ * 4);
    float* invdeg= (float*)alloc((size_t)N_ * 4);
    int* degi    = (int*)alloc((size_t)N_ * 4);
    int* csr_off = (int*)alloc((size_t)(N_ + 1) * 4);
    int* cursor  = (int*)alloc((size_t)N_ * 4);
    int2* meta   = (int2*)alloc((size_t)E_ * 8);
    int* rs      = (int*)alloc((size_t)(B_ + 1) * 4);
    int* partial = (int*)alloc((size_t)128 * 4);

    const int SCAN_NB = (N_ + 1023) / 1024;  // 98

    // degree histogram + norms
    hipMemsetAsync(degi, 0, (size_t)N_ * 4, stream);
    k_hist<<<(E_ + 255) / 256, 256, 0, stream>>>(dst, degi, E_);
    k_norm<<<(N_ + 255) / 256, 256, 0, stream>>>(degi, nrm, invdeg, N_);

    // CSR offsets = exclusive scan of degi
    k_scan1<<<SCAN_NB, 1024, 0, stream>>>(degi, csr_off, partial, N_);
    k_scan2<<<1, 128, 0, stream>>>(partial, SCAN_NB, csr_off + N_);
    k_scan3<<<SCAN_NB, 1024, 0, stream>>>(csr_off, partial, N_);
    hipMemcpyAsync(cursor, csr_off, (size_t)N_ * 4, hipMemcpyDeviceToDevice, stream);
    k_scatter<<<(E_ + 255) / 256, 256, 0, stream>>>(dst, src, edge_feats, nrm,
                                                    cursor, meta, ef16, E_);

    // graph segment boundaries (graph_ids sorted)
    k_rowstart<<<(B_ + 1 + 255) / 256, 256, 0, stream>>>(graph_ids, rs, N_, B_);

    // weights -> bf16 transposed swizzled; We -> packed half2
    k_convW<<<(L_ * 384 * (KP_ / 8) + 255) / 256, 256, 0, stream>>>(Wn, WnT, L_, H_, H_, KP_, 384);
    k_convWeh<<<(L_ * 8 * H_ + 255) / 256, 256, 0, stream>>>(We, Weh);
    k_convW<<<(4 * 640 * (KP_ / 8) + 255) / 256, 256, 0, stream>>>(W1, W1T, 4, H_, 2 * H_, KP_, 640);
    k_convW<<<(4 * 384 * (640 / 8) + 255) / 256, 256, 0, stream>>>(W2, W2T, 4, 2 * H_, H_, 640, 384);

    // h = node_emb[nt] + vn_emb (pads zeroed); vn = vn_emb
    k_hinit<<<N_, 320, 0, stream>>>(node_types, node_emb, vn_emb, h_bf);
    k_vninit<<<B_, 320, 0, stream>>>(vn_emb, vn);

    dim3 gx(MPAD / MB, 3);    // x GEMM: 782 x 3
    dim3 gz(B_ / MB, 5);      // z GEMM: 16 x 5
    dim3 gv(B_ / MB, 3);      // vn GEMM: 16 x 3

    for (int l = 0; l < L_; l++) {
        // x = h @ Wn[l] + bn[l]  -> bf16 LINEAR
        k_bgemm<<<gx, 256, 0, stream>>>(h_bf, WnT + (size_t)l * 384 * KP_,
                                        N_, H_, KP_,
                                        bn + (size_t)l * H_, nullptr, nullptr, 0,
                                        nullptr, 0, x_bf, KP_, 0);
        if (l < L_ - 1) {
            k_vtmp<<<B_, 256, 0, stream>>>(h_bf, vn, rs, vtmp_bf);
            // z = relu(bn1(vtmp @ W1 + b1)) -> bf16 swizzled [B][640]
            k_bgemm<<<gz, 256, 0, stream>>>(vtmp_bf, W1T + (size_t)l * 640 * KP_,
                                            B_, 2 * H_, KP_,
                                            b1 + (size_t)l * 2 * H_,
                                            g1 + (size_t)l * 2 * H_, be1 + (size_t)l * 2 * H_, 1,
                                            nullptr, 0, z_bf, 640, 1);
            // vn = relu(bn2(z @ W2 + b2)) -> fp32 [B][300]
            k_bgemm<<<gv, 256, 0, stream>>>(z_bf, W2T + (size_t)l * 384 * 640,
                                            B_, H_, 640,
                                            b2 + (size_t)l * H_,
                                            g2 + (size_t)l * H_, be2 + (size_t)l * H_, 1,
                                            vn, H_, nullptr, 0, 0);
        }
        // h = bn(agg + relu(x+root)*invdeg) (+relu/+vn_next if l<L-1)
        k_agg<<<N_ / ANODES, 320, 0, stream>>>(x_bf, h_bf, csr_off, meta, ef16,
                                               Weh + (size_t)l * 8 * H_, be + (size_t)l * H_,
                                               invdeg,
                                               root + (size_t)l * H_,
                                               gamma + (size_t)l * H_, beta + (size_t)l * H_,
                                               (l < L_ - 1) ? vn : nullptr, graph_ids,
                                               (l < L_ - 1) ? 1 : 0);
    }

    // fused readout: gmean -> head
    k_readout<<<B_, 256, 0, stream>>>(h_bf, rs, pW, pb, out);
}